// Round 8
// baseline (429.471 us; speedup 1.0000x reference)
//
#include <hip/hip_runtime.h>
#include <stdint.h>

// Problem constants
#define B_  2
#define T_  2048
#define C_  2048
#define H_  16
#define D_  128
#define BH_ 32        // B*H
#define M_  4096      // B*T

typedef __attribute__((ext_vector_type(8))) __bf16  bf16x8;
typedef __attribute__((ext_vector_type(4))) float   floatx4;
typedef __attribute__((ext_vector_type(4))) ushort  ushortx4;

__device__ __forceinline__ ushort f2bf(float f) {
    union { float f; uint32_t u; } v; v.f = f;
    return (ushort)((v.u + 0x7fffu + ((v.u >> 16) & 1u)) >> 16);
}

__device__ __forceinline__ float bf2f(ushort u) {
    union { uint32_t u; float f; } v; v.u = ((uint32_t)u) << 16;
    return v.f;
}

__device__ __forceinline__ floatx4 mfma_bf16(bf16x8 a, bf16x8 b, floatx4 c) {
    return __builtin_amdgcn_mfma_f32_16x16x32_bf16(a, b, c, 0, 0, 0);
}

// async global->LDS, 16B per lane; lds dest = wave-uniform base + lane*16
__device__ __forceinline__ void async16(const ushort* g, ushort* l) {
    __builtin_amdgcn_global_load_lds(
        (const __attribute__((address_space(1))) uint32_t*)g,
        (__attribute__((address_space(3))) uint32_t*)l, 16, 0, 0);
}

// ---------------------------------------------------------------------------
// x f32 -> bf16 (vectorized 4-wide)
// ---------------------------------------------------------------------------
__global__ __launch_bounds__(256) void convert_bf16(
    const float* __restrict__ X, ushort* __restrict__ Xb)
{
    const int i = blockIdx.x * 256 + threadIdx.x;
    const float4 v = ((const float4*)X)[i];
    ushortx4 p = { f2bf(v.x), f2bf(v.y), f2bf(v.z), f2bf(v.w) };
    ((ushortx4*)Xb)[i] = p;
}

// ---------------------------------------------------------------------------
// Transpose + convert: W f32 [K][N] -> Wt bf16 [N][K]
// ---------------------------------------------------------------------------
__global__ __launch_bounds__(256) void transpose_w(
    const float* __restrict__ W, ushort* __restrict__ Wt, int Kdim, int Ndim)
{
    __shared__ float tile[32][33];
    const int n0 = blockIdx.x * 32, k0 = blockIdx.y * 32;
    const int tx = threadIdx.x, ty = threadIdx.y;
    #pragma unroll
    for (int j = 0; j < 4; j++)
        tile[ty + j*8][tx] = W[(size_t)(k0 + ty + j*8) * Ndim + n0 + tx];
    __syncthreads();
    #pragma unroll
    for (int j = 0; j < 4; j++)
        Wt[(size_t)(n0 + ty + j*8) * Kdim + k0 + tx] = f2bf(tile[tx][ty + j*8]);
}

// ---------------------------------------------------------------------------
// Plain GEMM (m97 structure): C[M][N] = A_bf16 @ Bt_bf16^T, C f32. (proj)
// ---------------------------------------------------------------------------
#define BM 128
#define BN 128
#define BK 32

__global__ __launch_bounds__(256) void gemm_bt(
    const ushort* __restrict__ A, const ushort* __restrict__ Bt,
    float* __restrict__ Co, int Ndim, int Kdim)
{
    __shared__ __align__(16) ushort As[BM * BK];
    __shared__ __align__(16) ushort Bs[BN * BK];
    const int tid  = threadIdx.x;
    const int lane = tid & 63;
    const int w    = tid >> 6;
    const int wm   = (w >> 1) * 64;
    const int wn   = (w & 1) * 64;
    const int lr   = lane & 15;
    const int quad = lane >> 4;
    const int srow = lane >> 2;
    const int soff = (lane & 3) * 8;

    const ushort* Ablk = A  + (size_t)(blockIdx.y * BM) * Kdim;
    const ushort* Bblk = Bt + (size_t)(blockIdx.x * BN) * Kdim;

    floatx4 acc[4][4];
    #pragma unroll
    for (int i = 0; i < 4; i++)
        #pragma unroll
        for (int j = 0; j < 4; j++)
            acc[i][j] = (floatx4){0.f, 0.f, 0.f, 0.f};

    for (int k0 = 0; k0 < Kdim; k0 += BK) {
        __syncthreads();
        #pragma unroll
        for (int j = 0; j < 2; j++) {
            const int row = w * 32 + j * 16 + srow;
            async16(Ablk + (size_t)row * Kdim + k0 + soff,
                    As + (w * 32 + j * 16) * BK);
            async16(Bblk + (size_t)row * Kdim + k0 + soff,
                    Bs + (w * 32 + j * 16) * BK);
        }
        __syncthreads();

        bf16x8 af[4], bfr[4];
        #pragma unroll
        for (int mi = 0; mi < 4; mi++)
            af[mi] = *(const bf16x8*)(&As[(wm + mi*16 + lr) * BK + quad * 8]);
        #pragma unroll
        for (int ni = 0; ni < 4; ni++)
            bfr[ni] = *(const bf16x8*)(&Bs[(wn + ni*16 + lr) * BK + quad * 8]);
        #pragma unroll
        for (int mi = 0; mi < 4; mi++)
            #pragma unroll
            for (int ni = 0; ni < 4; ni++)
                acc[mi][ni] = mfma_bf16(af[mi], bfr[ni], acc[mi][ni]);
    }

    const size_t row0 = (size_t)blockIdx.y * BM + wm;
    const size_t col0 = (size_t)blockIdx.x * BN + wn;
    #pragma unroll
    for (int mi = 0; mi < 4; mi++)
        #pragma unroll
        for (int ni = 0; ni < 4; ni++)
            #pragma unroll
            for (int r = 0; r < 4; r++)
                Co[(row0 + mi*16 + quad*4 + r) * (size_t)Ndim + col0 + ni*16 + lr]
                    = acc[mi][ni][r];
}

// ---------------------------------------------------------------------------
// Fused QKV GEMM (exact R0 version): epilogue produces flash-ready tensors.
// ---------------------------------------------------------------------------
__global__ __launch_bounds__(256) void gemm_qkv(
    const ushort* __restrict__ A, const ushort* __restrict__ Bt,
    const float* __restrict__ cosb, const float* __restrict__ sinb,
    ushort* __restrict__ qb, ushort* __restrict__ kbf, ushort* __restrict__ vt)
{
    __shared__ __align__(16) ushort smem[17408];   // 34,816 B
    ushort* As = smem;          // 128*32
    ushort* Bs = smem + 4096;   // 128*32

    const int tid  = threadIdx.x;
    const int lane = tid & 63;
    const int w    = tid >> 6;
    const int wm   = (w >> 1) * 64;
    const int wn   = (w & 1) * 64;
    const int lr   = lane & 15;
    const int quad = lane >> 4;
    const int srow = lane >> 2;
    const int soff = (lane & 3) * 8;

    const int Kdim = C_;
    const ushort* Ablk = A  + (size_t)(blockIdx.y * BM) * Kdim;
    const ushort* Bblk = Bt + (size_t)(blockIdx.x * BN) * Kdim;

    floatx4 acc[4][4];
    #pragma unroll
    for (int i = 0; i < 4; i++)
        #pragma unroll
        for (int j = 0; j < 4; j++)
            acc[i][j] = (floatx4){0.f, 0.f, 0.f, 0.f};

    for (int k0 = 0; k0 < Kdim; k0 += BK) {
        __syncthreads();
        #pragma unroll
        for (int j = 0; j < 2; j++) {
            const int row = w * 32 + j * 16 + srow;
            async16(Ablk + (size_t)row * Kdim + k0 + soff,
                    As + (w * 32 + j * 16) * BK);
            async16(Bblk + (size_t)row * Kdim + k0 + soff,
                    Bs + (w * 32 + j * 16) * BK);
        }
        __syncthreads();

        bf16x8 af[4], bfr[4];
        #pragma unroll
        for (int mi = 0; mi < 4; mi++)
            af[mi] = *(const bf16x8*)(&As[(wm + mi*16 + lr) * BK + quad * 8]);
        #pragma unroll
        for (int ni = 0; ni < 4; ni++)
            bfr[ni] = *(const bf16x8*)(&Bs[(wn + ni*16 + lr) * BK + quad * 8]);
        #pragma unroll
        for (int mi = 0; mi < 4; mi++)
            #pragma unroll
            for (int ni = 0; ni < 4; ni++)
                acc[mi][ni] = mfma_bf16(af[mi], bfr[ni], acc[mi][ni]);
    }

    // ---- epilogue ----
    const int h   = blockIdx.x & 15;
    const int qt  = blockIdx.x >> 4;
    const int b   = blockIdx.y >> 4;
    const int t0g = (blockIdx.y & 15) * 128;
    const int bh  = b * 16 + h;

    __syncthreads();   // all frag reads done before smem reuse

    if (qt < 2) {
        // acc -> LDS [t][136] bf16
        #pragma unroll
        for (int mi = 0; mi < 4; mi++)
            #pragma unroll
            for (int ni = 0; ni < 4; ni++)
                #pragma unroll
                for (int r = 0; r < 4; r++) {
                    const int t = wm + mi*16 + quad*4 + r;
                    const int d = wn + ni*16 + lr;
                    smem[t * 136 + d] = f2bf(acc[mi][ni][r]);
                }
        __syncthreads();

        // readback: thread -> row t = tid>>1, d-chunks [c0,c0+32) and +64
        const int t  = tid >> 1;
        const int c0 = (tid & 1) * 32;
        bf16x8 x1v[4], x2v[4];
        #pragma unroll
        for (int u = 0; u < 4; u++) {
            x1v[u] = *(const bf16x8*)(smem + t * 136 + c0 + u * 8);
            x2v[u] = *(const bf16x8*)(smem + t * 136 + 64 + c0 + u * 8);
        }
        const float4* cp4 = (const float4*)(cosb + (size_t)(t0g + t) * 64 + c0);
        const float4* sp4 = (const float4*)(sinb + (size_t)(t0g + t) * 64 + c0);
        ushort* outp = (qt == 0 ? qb : kbf) + ((size_t)bh * T_ + t0g + t) * D_;
        #pragma unroll
        for (int u = 0; u < 4; u++) {
            float cc[8], ss[8];
            *(float4*)(cc)     = cp4[u * 2];
            *(float4*)(cc + 4) = cp4[u * 2 + 1];
            *(float4*)(ss)     = sp4[u * 2];
            *(float4*)(ss + 4) = sp4[u * 2 + 1];
            ushortx4 lo0, lo1, hi0, hi1;
            #pragma unroll
            for (int e = 0; e < 8; e++) {
                const float x1 = (float)x1v[u][e];
                const float x2 = (float)x2v[u][e];
                const ushort vlo = f2bf(x1 * cc[e] - x2 * ss[e]);
                const ushort vhi = f2bf(x1 * ss[e] + x2 * cc[e]);
                if (e < 4) { lo0[e] = vlo; hi0[e] = vhi; }
                else       { lo1[e-4] = vlo; hi1[e-4] = vhi; }
            }
            *(ushortx4*)(outp + c0 + u*8)          = lo0;
            *(ushortx4*)(outp + c0 + u*8 + 4)      = lo1;
            *(ushortx4*)(outp + 64 + c0 + u*8)     = hi0;
            *(ushortx4*)(outp + 64 + c0 + u*8 + 4) = hi1;
        }
    } else {
        // v: acc -> LDS transposed [d][128], units swizzled by d
        #pragma unroll
        for (int mi = 0; mi < 4; mi++)
            #pragma unroll
            for (int ni = 0; ni < 4; ni++)
                #pragma unroll
                for (int r = 0; r < 4; r++) {
                    const int t = wm + mi*16 + quad*4 + r;
                    const int d = wn + ni*16 + lr;
                    smem[d * 128 + (t & 7) + 8 * ((t >> 3) ^ (d & 15))]
                        = f2bf(acc[mi][ni][r]);
                }
        __syncthreads();

        const int d    = tid >> 1;
        const int half = tid & 1;
        ushort* outp = vt + ((size_t)bh * D_ + d) * T_ + t0g + half * 64;
        #pragma unroll
        for (int u = 0; u < 8; u++) {
            const int gu = half * 8 + u;
            bf16x8 vv = *(const bf16x8*)(smem + d * 128 + 8 * (gu ^ (d & 15)));
            *(bf16x8*)(outp + u * 8) = vv;
        }
    }
}

// ---------------------------------------------------------------------------
// Cooperative causal flash attention, static-shift softmax.
// R8: XCD-locality block mapping. With round-robin dispatch (xcd = bid%8),
//   bh = xcd + 8*(j>>5), m = 31-(j&31)  (j = bid>>3)
//   puts all 32 blocks that read one head's K/V (2 MB) on ONE XCD in a
//   contiguous launch window (~2 concurrent bh/XCD ~= 4MB ~= L2), so K/V is
//   HBM-fetched once per head (540 MB -> ~64 MB) and per-tile DMA becomes
//   L2-hit; R6's issue-early double-buffer hides that latency. Pure
//   bijection: wrong dispatch assumption costs perf only, never correctness.
//   Everything else identical to the verified R6 kernel.
// Output bf16 [M][C] so the proj GEMM consumes it directly.
// ---------------------------------------------------------------------------
__global__ __launch_bounds__(256, 2) void flash_attn(
    const ushort* __restrict__ qb, const ushort* __restrict__ kb,
    const ushort* __restrict__ vt, ushort* __restrict__ attnoutb)
{
    __shared__ __align__(16) ushort kt_s[2][64 * 128];   // [key][d], units ^key
    __shared__ __align__(16) ushort vt_s[2][128 * 64];   // [d][key], units ^d
    __shared__ __align__(16) ushort pl_s[4][16 * 40];    // per-wave P tile

    const int w    = threadIdx.x >> 6;
    const int lane = threadIdx.x & 63;
    const int lr   = lane & 15;
    const int quad = lane >> 4;

    // XCD-locality mapping: all 32 m-blocks of a bh land on one XCD,
    // launched contiguously (longest key-ranges first within the group).
    const int bid = (int)blockIdx.x;        // 0..1023
    const int xcd = bid & 7;
    const int j   = bid >> 3;               // 0..127
    const int bh  = xcd + 8 * (j >> 5);     // 4 bh-groups per XCD
    const int m   = 31 - (j & 31);          // longest first
    const int qt = 4 * m + w;
    const int qbase = qt * 16;
    const int nk = m + 1;
    const int bb = bh >> 4, hh = bh & 15;

    const ushort* kbp = kb + (size_t)bh * T_ * D_;
    const ushort* vbp = vt + (size_t)bh * D_ * T_;
    ushort* pl = pl_s[w];

    const int krow4 = lane >> 4;
    const int kunit = lane & 15;
    const int vrow8 = lane >> 3;
    const int vunit = lane & 7;

    bf16x8 qf[4];
    const ushort* qrow = qb + ((size_t)bh * T_ + qbase + lr) * D_ + quad * 8;
    #pragma unroll
    for (int kc = 0; kc < 4; kc++)
        qf[kc] = *(const bf16x8*)(qrow + kc * 32);

    floatx4 o[8];
    #pragma unroll
    for (int dc = 0; dc < 8; dc++) o[dc] = (floatx4){0.f, 0.f, 0.f, 0.f};
    floatx4 lac = (floatx4){0.f, 0.f, 0.f, 0.f};

    const __bf16 one = (__bf16)1.0f;
    const bf16x8 ones = {one, one, one, one, one, one, one, one};
    const float SCL  = 0.08838834764831845f * 1.4426950408889634f;
    const float BIAS = 23.083120654223414f;

    // ---- prologue: stage tile 0 into buf 0 ----
    {
        const int kb0 = 0;
        #pragma unroll
        for (int j2 = 0; j2 < 4; j2++) {
            const int row = w * 16 + j2 * 4 + krow4;
            const ushort* gp = kbp + (size_t)(kb0 + row) * D_
                                   + ((kunit ^ (row & 15)) << 3);
            async16(gp, kt_s[0] + (w * 16 + j2 * 4) * 128);
        }
        #pragma unroll
        for (int j2 = 0; j2 < 4; j2++) {
            const int row = w * 32 + j2 * 8 + vrow8;
            const ushort* gp = vbp + (size_t)row * T_ + kb0
                                   + ((vunit ^ (row & 7)) << 3);
            async16(gp, vt_s[0] + (w * 32 + j2 * 8) * 64);
        }
    }
    __syncthreads();   // drains prologue DMAs (once per block)

    for (int kt = 0; kt < nk; ++kt) {
        const int bsel = kt & 1;
        const int kb0  = kt * 64;

        // ---- issue next tile's DMAs first (fly under compute) ----
        if (kt + 1 < nk) {
            const int kb1 = kb0 + 64;
            #pragma unroll
            for (int j2 = 0; j2 < 4; j2++) {
                const int row = w * 16 + j2 * 4 + krow4;
                const ushort* gp = kbp + (size_t)(kb1 + row) * D_
                                       + ((kunit ^ (row & 15)) << 3);
                async16(gp, kt_s[bsel ^ 1] + (w * 16 + j2 * 4) * 128);
            }
            #pragma unroll
            for (int j2 = 0; j2 < 4; j2++) {
                const int row = w * 32 + j2 * 8 + vrow8;
                const ushort* gp = vbp + (size_t)row * T_ + kb1
                                       + ((vunit ^ (row & 7)) << 3);
                async16(gp, vt_s[bsel ^ 1] + (w * 32 + j2 * 8) * 64);
            }
        }

        // ---- compute tile kt from buf bsel ----
        const ushort* kbuf = kt_s[bsel];
        const ushort* vbuf = vt_s[bsel];

        #pragma unroll
        for (int half = 0; half < 2; ++half) {
            floatx4 st[2];
            #pragma unroll
            for (int jj = 0; jj < 2; ++jj) {
                const int jx = half * 2 + jj;
                floatx4 s = (floatx4){0.f, 0.f, 0.f, 0.f};
                const int kl = jx * 16 + lr;
                #pragma unroll
                for (int kc = 0; kc < 4; kc++) {
                    bf16x8 af = *(const bf16x8*)(
                        kbuf + kl * 128 + ((((kc << 2) | quad) ^ lr) << 3));
                    s = mfma_bf16(af, qf[kc], s);
                }
                st[jj] = s;
            }
            #pragma unroll
            for (int jj = 0; jj < 2; ++jj) {
                const int kg0 = kb0 + (half * 2 + jj) * 16 + quad * 4;
                float p[4];
                #pragma unroll
                for (int r = 0; r < 4; r++) {
                    float e = __builtin_amdgcn_exp2f(fmaf(st[jj][r], SCL, -BIAS));
                    p[r] = (kg0 + r > qbase + lr) ? 0.f : e;
                }
                uint2 pk;
                pk.x = (uint32_t)f2bf(p[0]) | ((uint32_t)f2bf(p[1]) << 16);
                pk.y = (uint32_t)f2bf(p[2]) | ((uint32_t)f2bf(p[3]) << 16);
                *(uint2*)(pl + lr * 40 + jj * 16 + quad * 4) = pk;
            }
            bf16x8 pf = *(const bf16x8*)(pl + lr * 40 + quad * 8);
            lac = mfma_bf16(pf, ones, lac);
            #pragma unroll
            for (int dc = 0; dc < 8; dc++) {
                const int d = dc * 16 + lr;
                bf16x8 vf = *(const bf16x8*)(
                    vbuf + d * 64 + ((((half << 2) | quad) ^ (lr & 7)) << 3));
                o[dc] = mfma_bf16(pf, vf, o[dc]);
            }
        }

        // one barrier per iter: drains (overlapped) kt+1 DMAs and certifies
        // all waves done reading buf bsel before iter kt+2 overwrites it
        __syncthreads();
    }

    #pragma unroll
    for (int dc = 0; dc < 8; dc++)
        #pragma unroll
        for (int r = 0; r < 4; r++) {
            const int trow = qbase + quad * 4 + r;
            attnoutb[((size_t)(bb * T_ + trow)) * C_ + hh * D_ + dc * 16 + lr]
                = f2bf(o[dc][r] / lac[r]);
        }
}

// ---------------------------------------------------------------------------
extern "C" void kernel_launch(void* const* d_in, const int* in_sizes, int n_in,
                              void* d_out, int out_size, void* d_ws, size_t ws_size,
                              hipStream_t stream)
{
    (void)in_sizes; (void)n_in; (void)out_size; (void)ws_size;
    const float* x     = (const float*)d_in[0];
    const float* cosb  = (const float*)d_in[1];
    const float* sinb  = (const float*)d_in[2];
    const float* Wqkv  = (const float*)d_in[3];
    const float* Wproj = (const float*)d_in[4];
    float* out = (float*)d_out;

    // Workspace (117,440,512 B used):
    //  xb   [M][C] bf16        @ 0          (16,777,216)
    //  Wtq  [3C][C] bf16       @ 16777216   (25,165,824)
    //  Wtp  [C][C] bf16        @ 41943040   ( 8,388,608)
    //  qb   [BH][T][D] bf16    @ 50331648   (16,777,216)
    //  kb   [BH][T][D] bf16    @ 67108864   (16,777,216)
    //  vt   [BH][D][T] bf16    @ 83886080   (16,777,216)
    //  attn [M][C] bf16        @ 100663296  (16,777,216)
    char* ws = (char*)d_ws;
    ushort* xb       = (ushort*)(ws);
    ushort* Wtq      = (ushort*)(ws + 16777216);
    ushort* Wtp      = (ushort*)(ws + 41943040);
    ushort* qb       = (ushort*)(ws + 50331648);
    ushort* kbf      = (ushort*)(ws + 67108864);
    ushort* vt       = (ushort*)(ws + 83886080);
    ushort* attnoutb = (ushort*)(ws + 100663296);

    dim3 tb32(32, 8);
    transpose_w<<<dim3(3 * C_ / 32, C_ / 32), tb32, 0, stream>>>(Wqkv, Wtq, C_, 3 * C_);
    transpose_w<<<dim3(C_ / 32, C_ / 32),     tb32, 0, stream>>>(Wproj, Wtp, C_, C_);
    convert_bf16<<<(M_ * C_ / 4) / 256, 256, 0, stream>>>(x, xb);

    gemm_qkv<<<dim3(3 * C_ / BN, M_ / BM), 256, 0, stream>>>(
        xb, Wtq, cosb, sinb, qb, kbf, vt);

    flash_attn<<<BH_ * 32, 256, 0, stream>>>(qb, kbf, vt, attnoutb);

    gemm_bt<<<dim3(C_ / BN, M_ / BM), 256, 0, stream>>>(attnoutb, Wtp, out, C_, C_);
}

// Round 9
// 382.705 us; speedup vs baseline: 1.1222x; 1.1222x over previous
//
#include <hip/hip_runtime.h>
#include <stdint.h>

// Problem constants
#define B_  2
#define T_  2048
#define C_  2048
#define H_  16
#define D_  128
#define BH_ 32        // B*H
#define M_  4096      // B*T

typedef __attribute__((ext_vector_type(8))) __bf16  bf16x8;
typedef __attribute__((ext_vector_type(4))) float   floatx4;
typedef __attribute__((ext_vector_type(4))) ushort  ushortx4;

__device__ __forceinline__ ushort f2bf(float f) {
    union { float f; uint32_t u; } v; v.f = f;
    return (ushort)((v.u + 0x7fffu + ((v.u >> 16) & 1u)) >> 16);
}

__device__ __forceinline__ float bf2f(ushort u) {
    union { uint32_t u; float f; } v; v.u = ((uint32_t)u) << 16;
    return v.f;
}

__device__ __forceinline__ floatx4 mfma_bf16(bf16x8 a, bf16x8 b, floatx4 c) {
    return __builtin_amdgcn_mfma_f32_16x16x32_bf16(a, b, c, 0, 0, 0);
}

// async global->LDS, 16B per lane; lds dest = wave-uniform base + lane*16
__device__ __forceinline__ void async16(const ushort* g, ushort* l) {
    __builtin_amdgcn_global_load_lds(
        (const __attribute__((address_space(1))) uint32_t*)g,
        (__attribute__((address_space(3))) uint32_t*)l, 16, 0, 0);
}

// ---------------------------------------------------------------------------
// x f32 -> bf16 (vectorized 4-wide)
// ---------------------------------------------------------------------------
__global__ __launch_bounds__(256) void convert_bf16(
    const float* __restrict__ X, ushort* __restrict__ Xb)
{
    const int i = blockIdx.x * 256 + threadIdx.x;
    const float4 v = ((const float4*)X)[i];
    ushortx4 p = { f2bf(v.x), f2bf(v.y), f2bf(v.z), f2bf(v.w) };
    ((ushortx4*)Xb)[i] = p;
}

// ---------------------------------------------------------------------------
// Transpose + convert: W f32 [K][N] -> Wt bf16 [N][K]
// ---------------------------------------------------------------------------
__global__ __launch_bounds__(256) void transpose_w(
    const float* __restrict__ W, ushort* __restrict__ Wt, int Kdim, int Ndim)
{
    __shared__ float tile[32][33];
    const int n0 = blockIdx.x * 32, k0 = blockIdx.y * 32;
    const int tx = threadIdx.x, ty = threadIdx.y;
    #pragma unroll
    for (int j = 0; j < 4; j++)
        tile[ty + j*8][tx] = W[(size_t)(k0 + ty + j*8) * Ndim + n0 + tx];
    __syncthreads();
    #pragma unroll
    for (int j = 0; j < 4; j++)
        Wt[(size_t)(n0 + ty + j*8) * Kdim + k0 + tx] = f2bf(tile[tx][ty + j*8]);
}

// ---------------------------------------------------------------------------
// Proj GEMM, R9: m97 tile + LDS double-buffer, issue-early staging, ONE
// barrier per K-iter (R6-flash transform). Stage of tile t+1 is issued
// before compute of tile t; the single __syncthreads' implicit vmcnt(0)
// drain is covered by the intervening ds_read+MFMA work.
// ---------------------------------------------------------------------------
#define BM 128
#define BN 128
#define BK 32

__global__ __launch_bounds__(256) void gemm_bt(
    const ushort* __restrict__ A, const ushort* __restrict__ Bt,
    float* __restrict__ Co, int Ndim, int Kdim)
{
    __shared__ __align__(16) ushort smem[16384];   // 2 x (As 4096 + Bs 4096)
    const int tid  = threadIdx.x;
    const int lane = tid & 63;
    const int w    = tid >> 6;
    const int wm   = (w >> 1) * 64;
    const int wn   = (w & 1) * 64;
    const int lr   = lane & 15;
    const int quad = lane >> 4;
    const int srow = lane >> 2;
    const int soff = (lane & 3) * 8;

    const ushort* Ablk = A  + (size_t)(blockIdx.y * BM) * Kdim;
    const ushort* Bblk = Bt + (size_t)(blockIdx.x * BN) * Kdim;

    floatx4 acc[4][4];
    #pragma unroll
    for (int i = 0; i < 4; i++)
        #pragma unroll
        for (int j = 0; j < 4; j++)
            acc[i][j] = (floatx4){0.f, 0.f, 0.f, 0.f};

    // prologue: stage tile 0 into buf 0
    #pragma unroll
    for (int j = 0; j < 2; j++) {
        const int row = w * 32 + j * 16 + srow;
        async16(Ablk + (size_t)row * Kdim + soff,
                smem + (w * 32 + j * 16) * BK);
        async16(Bblk + (size_t)row * Kdim + soff,
                smem + 4096 + (w * 32 + j * 16) * BK);
    }
    __syncthreads();

    #pragma unroll 2
    for (int t = 0; t < 64; ++t) {
        const int off  = (t & 1) << 13;          // 8192 ushorts per buf pair
        const int noff = off ^ 8192;
        const int k1   = (t + 1) * BK;

        // issue next tile's DMAs first (fly under compute)
        if (k1 < Kdim) {
            #pragma unroll
            for (int j = 0; j < 2; j++) {
                const int row = w * 32 + j * 16 + srow;
                async16(Ablk + (size_t)row * Kdim + k1 + soff,
                        smem + noff + (w * 32 + j * 16) * BK);
                async16(Bblk + (size_t)row * Kdim + k1 + soff,
                        smem + noff + 4096 + (w * 32 + j * 16) * BK);
            }
        }

        const ushort* As = smem + off;
        const ushort* Bs = smem + off + 4096;
        bf16x8 af[4], bfr[4];
        #pragma unroll
        for (int mi = 0; mi < 4; mi++)
            af[mi] = *(const bf16x8*)(&As[(wm + mi*16 + lr) * BK + quad * 8]);
        #pragma unroll
        for (int ni = 0; ni < 4; ni++)
            bfr[ni] = *(const bf16x8*)(&Bs[(wn + ni*16 + lr) * BK + quad * 8]);
        #pragma unroll
        for (int mi = 0; mi < 4; mi++)
            #pragma unroll
            for (int ni = 0; ni < 4; ni++)
                acc[mi][ni] = mfma_bf16(af[mi], bfr[ni], acc[mi][ni]);

        __syncthreads();   // drains (overlapped) t+1 DMAs; guards buf reuse
    }

    const size_t row0 = (size_t)blockIdx.y * BM + wm;
    const size_t col0 = (size_t)blockIdx.x * BN + wn;
    #pragma unroll
    for (int mi = 0; mi < 4; mi++)
        #pragma unroll
        for (int ni = 0; ni < 4; ni++)
            #pragma unroll
            for (int r = 0; r < 4; r++)
                Co[(row0 + mi*16 + quad*4 + r) * (size_t)Ndim + col0 + ni*16 + lr]
                    = acc[mi][ni][r];
}

// ---------------------------------------------------------------------------
// Fused QKV GEMM, R9: same dbuf/issue-early/1-barrier K-loop. The 2x(As+Bs)
// double buffer (32,768 B) fits inside the existing 34,816 B epilogue union,
// so LDS size, VGPR, grid and epilogue are unchanged from the verified R0.
// ---------------------------------------------------------------------------
__global__ __launch_bounds__(256) void gemm_qkv(
    const ushort* __restrict__ A, const ushort* __restrict__ Bt,
    const float* __restrict__ cosb, const float* __restrict__ sinb,
    ushort* __restrict__ qb, ushort* __restrict__ kbf, ushort* __restrict__ vt)
{
    __shared__ __align__(16) ushort smem[17408];   // 34,816 B (epilogue union)

    const int tid  = threadIdx.x;
    const int lane = tid & 63;
    const int w    = tid >> 6;
    const int wm   = (w >> 1) * 64;
    const int wn   = (w & 1) * 64;
    const int lr   = lane & 15;
    const int quad = lane >> 4;
    const int srow = lane >> 2;
    const int soff = (lane & 3) * 8;

    const int Kdim = C_;
    const ushort* Ablk = A  + (size_t)(blockIdx.y * BM) * Kdim;
    const ushort* Bblk = Bt + (size_t)(blockIdx.x * BN) * Kdim;

    floatx4 acc[4][4];
    #pragma unroll
    for (int i = 0; i < 4; i++)
        #pragma unroll
        for (int j = 0; j < 4; j++)
            acc[i][j] = (floatx4){0.f, 0.f, 0.f, 0.f};

    // prologue: stage tile 0 into buf 0
    #pragma unroll
    for (int j = 0; j < 2; j++) {
        const int row = w * 32 + j * 16 + srow;
        async16(Ablk + (size_t)row * Kdim + soff,
                smem + (w * 32 + j * 16) * BK);
        async16(Bblk + (size_t)row * Kdim + soff,
                smem + 4096 + (w * 32 + j * 16) * BK);
    }
    __syncthreads();

    #pragma unroll 2
    for (int t = 0; t < 64; ++t) {
        const int off  = (t & 1) << 13;
        const int noff = off ^ 8192;
        const int k1   = (t + 1) * BK;

        if (k1 < Kdim) {
            #pragma unroll
            for (int j = 0; j < 2; j++) {
                const int row = w * 32 + j * 16 + srow;
                async16(Ablk + (size_t)row * Kdim + k1 + soff,
                        smem + noff + (w * 32 + j * 16) * BK);
                async16(Bblk + (size_t)row * Kdim + k1 + soff,
                        smem + noff + 4096 + (w * 32 + j * 16) * BK);
            }
        }

        const ushort* As = smem + off;
        const ushort* Bs = smem + off + 4096;
        bf16x8 af[4], bfr[4];
        #pragma unroll
        for (int mi = 0; mi < 4; mi++)
            af[mi] = *(const bf16x8*)(&As[(wm + mi*16 + lr) * BK + quad * 8]);
        #pragma unroll
        for (int ni = 0; ni < 4; ni++)
            bfr[ni] = *(const bf16x8*)(&Bs[(wn + ni*16 + lr) * BK + quad * 8]);
        #pragma unroll
        for (int mi = 0; mi < 4; mi++)
            #pragma unroll
            for (int ni = 0; ni < 4; ni++)
                acc[mi][ni] = mfma_bf16(af[mi], bfr[ni], acc[mi][ni]);

        __syncthreads();   // drains (overlapped) t+1 DMAs; guards buf reuse
    }

    // ---- epilogue ----
    const int h   = blockIdx.x & 15;
    const int qt  = blockIdx.x >> 4;
    const int b   = blockIdx.y >> 4;
    const int t0g = (blockIdx.y & 15) * 128;
    const int bh  = b * 16 + h;

    if (qt < 2) {
        // acc -> LDS [t][136] bf16
        #pragma unroll
        for (int mi = 0; mi < 4; mi++)
            #pragma unroll
            for (int ni = 0; ni < 4; ni++)
                #pragma unroll
                for (int r = 0; r < 4; r++) {
                    const int t = wm + mi*16 + quad*4 + r;
                    const int d = wn + ni*16 + lr;
                    smem[t * 136 + d] = f2bf(acc[mi][ni][r]);
                }
        __syncthreads();

        // readback: thread -> row t = tid>>1, d-chunks [c0,c0+32) and +64
        const int t  = tid >> 1;
        const int c0 = (tid & 1) * 32;
        bf16x8 x1v[4], x2v[4];
        #pragma unroll
        for (int u = 0; u < 4; u++) {
            x1v[u] = *(const bf16x8*)(smem + t * 136 + c0 + u * 8);
            x2v[u] = *(const bf16x8*)(smem + t * 136 + 64 + c0 + u * 8);
        }
        const float4* cp4 = (const float4*)(cosb + (size_t)(t0g + t) * 64 + c0);
        const float4* sp4 = (const float4*)(sinb + (size_t)(t0g + t) * 64 + c0);
        ushort* outp = (qt == 0 ? qb : kbf) + ((size_t)bh * T_ + t0g + t) * D_;
        #pragma unroll
        for (int u = 0; u < 4; u++) {
            float cc[8], ss[8];
            *(float4*)(cc)     = cp4[u * 2];
            *(float4*)(cc + 4) = cp4[u * 2 + 1];
            *(float4*)(ss)     = sp4[u * 2];
            *(float4*)(ss + 4) = sp4[u * 2 + 1];
            ushortx4 lo0, lo1, hi0, hi1;
            #pragma unroll
            for (int e = 0; e < 8; e++) {
                const float x1 = (float)x1v[u][e];
                const float x2 = (float)x2v[u][e];
                const ushort vlo = f2bf(x1 * cc[e] - x2 * ss[e]);
                const ushort vhi = f2bf(x1 * ss[e] + x2 * cc[e]);
                if (e < 4) { lo0[e] = vlo; hi0[e] = vhi; }
                else       { lo1[e-4] = vlo; hi1[e-4] = vhi; }
            }
            *(ushortx4*)(outp + c0 + u*8)          = lo0;
            *(ushortx4*)(outp + c0 + u*8 + 4)      = lo1;
            *(ushortx4*)(outp + 64 + c0 + u*8)     = hi0;
            *(ushortx4*)(outp + 64 + c0 + u*8 + 4) = hi1;
        }
    } else {
        // v: acc -> LDS transposed [d][128], units swizzled by d
        #pragma unroll
        for (int mi = 0; mi < 4; mi++)
            #pragma unroll
            for (int ni = 0; ni < 4; ni++)
                #pragma unroll
                for (int r = 0; r < 4; r++) {
                    const int t = wm + mi*16 + quad*4 + r;
                    const int d = wn + ni*16 + lr;
                    smem[d * 128 + (t & 7) + 8 * ((t >> 3) ^ (d & 15))]
                        = f2bf(acc[mi][ni][r]);
                }
        __syncthreads();

        const int d    = tid >> 1;
        const int half = tid & 1;
        ushort* outp = vt + ((size_t)bh * D_ + d) * T_ + t0g + half * 64;
        #pragma unroll
        for (int u = 0; u < 8; u++) {
            const int gu = half * 8 + u;
            bf16x8 vv = *(const bf16x8*)(smem + d * 128 + 8 * (gu ^ (d & 15)));
            *(bf16x8*)(outp + u * 8) = vv;
        }
    }
}

// ---------------------------------------------------------------------------
// Cooperative causal flash attention (R6-exact, best verified).
// Double-buffered K/V staging with issue-early/drain-late; one barrier/iter.
// Output bf16 [M][C] so the proj GEMM consumes it directly.
// ---------------------------------------------------------------------------
__global__ __launch_bounds__(256, 2) void flash_attn(
    const ushort* __restrict__ qb, const ushort* __restrict__ kb,
    const ushort* __restrict__ vt, ushort* __restrict__ attnoutb)
{
    __shared__ __align__(16) ushort kt_s[2][64 * 128];   // [key][d], units ^key
    __shared__ __align__(16) ushort vt_s[2][128 * 64];   // [d][key], units ^d
    __shared__ __align__(16) ushort pl_s[4][16 * 40];    // per-wave P tile

    const int w    = threadIdx.x >> 6;
    const int lane = threadIdx.x & 63;
    const int lr   = lane & 15;
    const int quad = lane >> 4;

    const int bh = blockIdx.x & 31;
    const int m  = 31 - (blockIdx.x >> 5);    // longest key-ranges first
    const int qt = 4 * m + w;
    const int qbase = qt * 16;
    const int nk = m + 1;
    const int bb = bh >> 4, hh = bh & 15;

    const ushort* kbp = kb + (size_t)bh * T_ * D_;
    const ushort* vbp = vt + (size_t)bh * D_ * T_;
    ushort* pl = pl_s[w];

    const int krow4 = lane >> 4;
    const int kunit = lane & 15;
    const int vrow8 = lane >> 3;
    const int vunit = lane & 7;

    bf16x8 qf[4];
    const ushort* qrow = qb + ((size_t)bh * T_ + qbase + lr) * D_ + quad * 8;
    #pragma unroll
    for (int kc = 0; kc < 4; kc++)
        qf[kc] = *(const bf16x8*)(qrow + kc * 32);

    floatx4 o[8];
    #pragma unroll
    for (int dc = 0; dc < 8; dc++) o[dc] = (floatx4){0.f, 0.f, 0.f, 0.f};
    floatx4 lac = (floatx4){0.f, 0.f, 0.f, 0.f};

    const __bf16 one = (__bf16)1.0f;
    const bf16x8 ones = {one, one, one, one, one, one, one, one};
    const float SCL  = 0.08838834764831845f * 1.4426950408889634f;
    const float BIAS = 23.083120654223414f;

    // ---- prologue: stage tile 0 into buf 0 ----
    {
        const int kb0 = 0;
        #pragma unroll
        for (int j = 0; j < 4; j++) {
            const int row = w * 16 + j * 4 + krow4;
            const ushort* gp = kbp + (size_t)(kb0 + row) * D_
                                   + ((kunit ^ (row & 15)) << 3);
            async16(gp, kt_s[0] + (w * 16 + j * 4) * 128);
        }
        #pragma unroll
        for (int j = 0; j < 4; j++) {
            const int row = w * 32 + j * 8 + vrow8;
            const ushort* gp = vbp + (size_t)row * T_ + kb0
                                   + ((vunit ^ (row & 7)) << 3);
            async16(gp, vt_s[0] + (w * 32 + j * 8) * 64);
        }
    }
    __syncthreads();   // drains prologue DMAs (once per block)

    for (int kt = 0; kt < nk; ++kt) {
        const int bsel = kt & 1;
        const int kb0  = kt * 64;

        // ---- issue next tile's DMAs first (fly under compute) ----
        if (kt + 1 < nk) {
            const int kb1 = kb0 + 64;
            #pragma unroll
            for (int j = 0; j < 4; j++) {
                const int row = w * 16 + j * 4 + krow4;
                const ushort* gp = kbp + (size_t)(kb1 + row) * D_
                                       + ((kunit ^ (row & 15)) << 3);
                async16(gp, kt_s[bsel ^ 1] + (w * 16 + j * 4) * 128);
            }
            #pragma unroll
            for (int j = 0; j < 4; j++) {
                const int row = w * 32 + j * 8 + vrow8;
                const ushort* gp = vbp + (size_t)row * T_ + kb1
                                       + ((vunit ^ (row & 7)) << 3);
                async16(gp, vt_s[bsel ^ 1] + (w * 32 + j * 8) * 64);
            }
        }

        // ---- compute tile kt from buf bsel ----
        const ushort* kbuf = kt_s[bsel];
        const ushort* vbuf = vt_s[bsel];

        #pragma unroll
        for (int half = 0; half < 2; ++half) {
            floatx4 st[2];
            #pragma unroll
            for (int jj = 0; jj < 2; ++jj) {
                const int jx = half * 2 + jj;
                floatx4 s = (floatx4){0.f, 0.f, 0.f, 0.f};
                const int kl = jx * 16 + lr;
                #pragma unroll
                for (int kc = 0; kc < 4; kc++) {
                    bf16x8 af = *(const bf16x8*)(
                        kbuf + kl * 128 + ((((kc << 2) | quad) ^ lr) << 3));
                    s = mfma_bf16(af, qf[kc], s);
                }
                st[jj] = s;
            }
            #pragma unroll
            for (int jj = 0; jj < 2; ++jj) {
                const int kg0 = kb0 + (half * 2 + jj) * 16 + quad * 4;
                float p[4];
                #pragma unroll
                for (int r = 0; r < 4; r++) {
                    float e = __builtin_amdgcn_exp2f(fmaf(st[jj][r], SCL, -BIAS));
                    p[r] = (kg0 + r > qbase + lr) ? 0.f : e;
                }
                uint2 pk;
                pk.x = (uint32_t)f2bf(p[0]) | ((uint32_t)f2bf(p[1]) << 16);
                pk.y = (uint32_t)f2bf(p[2]) | ((uint32_t)f2bf(p[3]) << 16);
                *(uint2*)(pl + lr * 40 + jj * 16 + quad * 4) = pk;
            }
            bf16x8 pf = *(const bf16x8*)(pl + lr * 40 + quad * 8);
            lac = mfma_bf16(pf, ones, lac);
            #pragma unroll
            for (int dc = 0; dc < 8; dc++) {
                const int d = dc * 16 + lr;
                bf16x8 vf = *(const bf16x8*)(
                    vbuf + d * 64 + ((((half << 2) | quad) ^ (lr & 7)) << 3));
                o[dc] = mfma_bf16(pf, vf, o[dc]);
            }
        }

        // one barrier per iter: drains (overlapped) kt+1 DMAs and certifies
        // all waves done reading buf bsel before iter kt+2 overwrites it
        __syncthreads();
    }

    #pragma unroll
    for (int dc = 0; dc < 8; dc++)
        #pragma unroll
        for (int r = 0; r < 4; r++) {
            const int trow = qbase + quad * 4 + r;
            attnoutb[((size_t)(bb * T_ + trow)) * C_ + hh * D_ + dc * 16 + lr]
                = f2bf(o[dc][r] / lac[r]);
        }
}

// ---------------------------------------------------------------------------
extern "C" void kernel_launch(void* const* d_in, const int* in_sizes, int n_in,
                              void* d_out, int out_size, void* d_ws, size_t ws_size,
                              hipStream_t stream)
{
    (void)in_sizes; (void)n_in; (void)out_size; (void)ws_size;
    const float* x     = (const float*)d_in[0];
    const float* cosb  = (const float*)d_in[1];
    const float* sinb  = (const float*)d_in[2];
    const float* Wqkv  = (const float*)d_in[3];
    const float* Wproj = (const float*)d_in[4];
    float* out = (float*)d_out;

    // Workspace (117,440,512 B used):
    //  xb   [M][C] bf16        @ 0          (16,777,216)
    //  Wtq  [3C][C] bf16       @ 16777216   (25,165,824)
    //  Wtp  [C][C] bf16        @ 41943040   ( 8,388,608)
    //  qb   [BH][T][D] bf16    @ 50331648   (16,777,216)
    //  kb   [BH][T][D] bf16    @ 67108864   (16,777,216)
    //  vt   [BH][D][T] bf16    @ 83886080   (16,777,216)
    //  attn [M][C] bf16        @ 100663296  (16,777,216)
    char* ws = (char*)d_ws;
    ushort* xb       = (ushort*)(ws);
    ushort* Wtq      = (ushort*)(ws + 16777216);
    ushort* Wtp      = (ushort*)(ws + 41943040);
    ushort* qb       = (ushort*)(ws + 50331648);
    ushort* kbf      = (ushort*)(ws + 67108864);
    ushort* vt       = (ushort*)(ws + 83886080);
    ushort* attnoutb = (ushort*)(ws + 100663296);

    dim3 tb32(32, 8);
    transpose_w<<<dim3(3 * C_ / 32, C_ / 32), tb32, 0, stream>>>(Wqkv, Wtq, C_, 3 * C_);
    transpose_w<<<dim3(C_ / 32, C_ / 32),     tb32, 0, stream>>>(Wproj, Wtp, C_, C_);
    convert_bf16<<<(M_ * C_ / 4) / 256, 256, 0, stream>>>(x, xb);

    gemm_qkv<<<dim3(3 * C_ / BN, M_ / BM), 256, 0, stream>>>(
        xb, Wtq, cosb, sinb, qb, kbf, vt);

    flash_attn<<<BH_ * 32, 256, 0, stream>>>(qb, kbf, vt, attnoutb);

    gemm_bt<<<dim3(C_ / BN, M_ / BM), 256, 0, stream>>>(attnoutb, Wtp, out, C_, C_);
}